// Round 5
// baseline (684.121 us; speedup 1.0000x reference)
//
#include <hip/hip_runtime.h>
#include <math.h>

// ---------------- problem constants ----------------
#define BQ    1024
#define NB    131072
#define DS    64
#define DF    256
#define KSEL  16

// ---------------- score kernel tiling ----------------
#define QT    128        // queries per block (4 waves, 2 m-tiles each)
#define BC    64         // blobs per chunk
#define PCH   64         // chunk stripes
#define NCHUNK (NB / BC)             // 2048
#define CHUNKS_PER_BLK (NCHUNK/PCH)  // 32
#define CPQ   (PCH * KSEL)           // 1024 candidates per query
#define CAPB  512                    // LDS survivor buffer entries
#define SAMPC 64                     // sample chunks (4096 blobs)
#define SEED_EPS 1e-4f

// Bprep layout per chunk: [split(2)][ntile(4)][kstep(4)][lane(64)][16B] = 32 KB
#define CH_BYTES   32768
#define SPLIT_OFF  16384

typedef __bf16 bf16x8 __attribute__((ext_vector_type(8)));
typedef float  f32x4  __attribute__((ext_vector_type(4)));
typedef unsigned long long u64;

__device__ __forceinline__ unsigned map_f32(float s) {
    unsigned u = __float_as_uint(s);
    return (u & 0x80000000u) ? ~u : (u | 0x80000000u);
}

__device__ __forceinline__ void async_cp16(const void* g, void* l) {
    __builtin_amdgcn_global_load_lds(
        (const __attribute__((address_space(1))) unsigned int*)g,
        (__attribute__((address_space(3))) unsigned int*)l, 16, 0, 0);
}

// ---------------- prep: fragment panels (coalesced) + m2 + log-alpha ----------------
__global__ __launch_bounds__(256)
void prep_kernel(const float* __restrict__ mu,
                 const float* __restrict__ log_var,
                 const float* __restrict__ raw_alpha,
                 char* __restrict__ bprep,
                 float* __restrict__ m2la)
{
    __shared__ float part[8][16];
    const int tid  = threadIdx.x;
    const int lane = tid & 63, ks = tid >> 6;
    const int nt   = blockIdx.x & 3, c = blockIdx.x >> 2;
    const int q    = lane >> 4, bl = lane & 15;
    const int blob = c * 64 + nt * 16 + bl;
    const int kq   = ks * 32 + q * 8;
    const int d0   = kq & 63;
    const bool lin = kq >= 64;            // false: iv row, true: mu*iv row

    const float* mrow = mu      + (size_t)blob * DS + d0;
    const float* vrow = log_var + (size_t)blob * DS + d0;

    bf16x8 h, l;
    float p = 0.0f;
    #pragma unroll
    for (int j = 0; j < 8; ++j) {
        float m  = mrow[j];
        float iv = __expf(-vrow[j]);
        float x  = lin ? (m * iv) : iv;
        __bf16 hb = (__bf16)x;
        h[j] = hb;
        l[j] = (__bf16)(x - (float)hb);
        if (lin) p += m * x;              // mu^2 * iv
    }
    size_t base = (size_t)c * CH_BYTES + nt * 4096 + ks * 1024 + lane * 16;
    *(bf16x8*)(bprep + base)             = h;   // coalesced: lane-contiguous 16B
    *(bf16x8*)(bprep + base + SPLIT_OFF) = l;

    if (lin) part[(ks - 2) * 4 + q][bl] = p;
    __syncthreads();
    if (tid < 16) {
        float s = 0.0f;
        #pragma unroll
        for (int r = 0; r < 8; ++r) s += part[r][tid];
        int b2 = c * 64 + nt * 16 + tid;
        m2la[b2 * 2]     = s;
        m2la[b2 * 2 + 1] = -log1pf(__expf(-raw_alpha[b2]));  // log sigmoid
    }
}

// ---------------- sampling: safe per-query cutoff seed ----------------
// seed = 16th-largest of 64 sub-stream maxes over sample (blobs 0..4095),
// computed with the EXACT same MFMA arithmetic as the score kernel.
// Lemma: <=16 substreams contain top-16-of-sample elements, so
// 16th-of-submaxes <= sample-16th <= true-16th  (safe lower bound).
__global__ __launch_bounds__(256)
void sample_kernel(const float* __restrict__ query,
                   const char* __restrict__ bprep,
                   const float* __restrict__ m2la,
                   const float* __restrict__ log_tau_p,
                   float* __restrict__ seeds)
{
    __shared__ __align__(16) short Bs[CH_BYTES / 2];

    const int tid   = threadIdx.x;
    const int lane  = tid & 63;
    const int quad  = lane >> 4;
    const int mrow  = lane & 15;
    const int wv    = tid >> 6;
    const int qbase = blockIdx.x * QT;

    const float nhit = -0.5f * expf(-log_tau_p[0]);

    bf16x8 ahi[2][4], alo[2][4];
    #pragma unroll
    for (int mt = 0; mt < 2; ++mt) {
        const float* qrow = query + (size_t)(qbase + wv * 32 + mt * 16 + mrow) * DS;
        #pragma unroll
        for (int ks = 0; ks < 4; ++ks) {
            int kq = ks * 32 + quad * 8;
            int d0 = kq & 63;
            bool lin = kq >= 64;
            bf16x8 h, l;
            #pragma unroll
            for (int j = 0; j < 8; ++j) {
                float v = qrow[d0 + j];
                float x = lin ? (-2.0f * v) : (v * v);
                __bf16 hb = (__bf16)x;
                h[j] = hb;
                l[j] = (__bf16)(x - (float)hb);
            }
            ahi[mt][ks] = h; alo[mt][ks] = l;
        }
    }

    const char* BsB = (const char*)Bs;
    float rmx[2][4][4];
    #pragma unroll
    for (int mt = 0; mt < 2; ++mt)
        #pragma unroll
        for (int nt = 0; nt < 4; ++nt)
            #pragma unroll
            for (int r = 0; r < 4; ++r) rmx[mt][nt][r] = -INFINITY;

    for (int c = 0; c < SAMPC; ++c) {
        __syncthreads();   // previous chunk's reads done
        {
            const char* src = bprep + (size_t)c * CH_BYTES;
            #pragma unroll
            for (int i = 0; i < 8; ++i) {
                int s = tid + i * 256;
                async_cp16(src + s * 16, (void*)(BsB + s * 16));
            }
        }
        __syncthreads();   // data ready (barrier drains vmcnt)

        float2 ml[4];
        #pragma unroll
        for (int nt = 0; nt < 4; ++nt)
            ml[nt] = *(const float2*)&m2la[(size_t)(c * BC + nt * 16 + mrow) * 2];

        #pragma unroll
        for (int nt = 0; nt < 4; ++nt) {
            f32x4 a0 = {0,0,0,0}, a1 = {0,0,0,0};
            #pragma unroll
            for (int ks = 0; ks < 4; ++ks) {
                bf16x8 bh = *(const bf16x8*)(BsB + nt * 4096 + ks * 1024 + lane * 16);
                bf16x8 bl = *(const bf16x8*)(BsB + SPLIT_OFF + nt * 4096 + ks * 1024 + lane * 16);
                a0 = __builtin_amdgcn_mfma_f32_16x16x32_bf16(ahi[0][ks], bh, a0, 0, 0, 0);
                a0 = __builtin_amdgcn_mfma_f32_16x16x32_bf16(ahi[0][ks], bl, a0, 0, 0, 0);
                a0 = __builtin_amdgcn_mfma_f32_16x16x32_bf16(alo[0][ks], bh, a0, 0, 0, 0);
                a1 = __builtin_amdgcn_mfma_f32_16x16x32_bf16(ahi[1][ks], bh, a1, 0, 0, 0);
                a1 = __builtin_amdgcn_mfma_f32_16x16x32_bf16(ahi[1][ks], bl, a1, 0, 0, 0);
                a1 = __builtin_amdgcn_mfma_f32_16x16x32_bf16(alo[1][ks], bh, a1, 0, 0, 0);
            }
            float m2 = ml[nt].x, la = ml[nt].y;
            #pragma unroll
            for (int r = 0; r < 4; ++r) {
                rmx[0][nt][r] = fmaxf(rmx[0][nt][r], fmaf(nhit, a0[r] + m2, la));
                rmx[1][nt][r] = fmaxf(rmx[1][nt][r], fmaf(nhit, a1[r] + m2, la));
            }
        }
    }
    __syncthreads();   // last chunk reads done; Bs reusable as float scratch

    float* Sm = (float*)Bs;    // [QT][64] = 32 KB
    #pragma unroll
    for (int mt = 0; mt < 2; ++mt)
        #pragma unroll
        for (int nt = 0; nt < 4; ++nt)
            #pragma unroll
            for (int r = 0; r < 4; ++r)
                Sm[(wv * 32 + mt * 16 + quad * 4 + r) * 64 + nt * 16 + mrow] = rmx[mt][nt][r];
    __syncthreads();

    if (tid < QT) {
        float* row = &Sm[tid * 64];
        float m = -INFINITY;
        for (int r = 0; r < KSEL; ++r) {
            m = -INFINITY; int pm = 0;
            for (int j = 0; j < 64; ++j) {
                float v = row[j];
                if (v > m) { m = v; pm = j; }
            }
            row[pm] = -INFINITY;
        }
        seeds[qbase + tid] = m - SEED_EPS;   // m = 16th-largest submax
    }
}

// ---------------- score + top-k: seeded screen, owner lists in LDS ----------------
__global__ __launch_bounds__(256, 3)
void score_topk_kernel(const float* __restrict__ query,
                       const char* __restrict__ bprep,
                       const float* __restrict__ m2la,
                       const float* __restrict__ log_tau_p,
                       const float* __restrict__ seeds,
                       u64* __restrict__ cand)
{
    __shared__ __align__(16) short Bs[CH_BYTES / 2];   // 32 KB
    __shared__ u64 buf[CAPB];                          // 4 KB survivor buffer
    __shared__ u64 lists[QT * KSEL];                   // 16 KB owner lists
    __shared__ int cnt2[2];

    const int tid   = threadIdx.x;
    const int lane  = tid & 63;
    const int quad  = lane >> 4;
    const int mrow  = lane & 15;
    const int wv    = tid >> 6;
    const int qt     = blockIdx.x >> 6;   // same-stripe blocks -> same XCD (x%8 = stripe%8)
    const int stripe = blockIdx.x & 63;
    const int qbase  = qt * QT;

    const float nhit = -0.5f * expf(-log_tau_p[0]);

    // persistent A fragments (hi+lo)
    bf16x8 ahi[2][4], alo[2][4];
    #pragma unroll
    for (int mt = 0; mt < 2; ++mt) {
        const float* qrow = query + (size_t)(qbase + wv * 32 + mt * 16 + mrow) * DS;
        #pragma unroll
        for (int ks = 0; ks < 4; ++ks) {
            int kq = ks * 32 + quad * 8;
            int d0 = kq & 63;
            bool lin = kq >= 64;
            bf16x8 h, l;
            #pragma unroll
            for (int j = 0; j < 8; ++j) {
                float v = qrow[d0 + j];
                float x = lin ? (-2.0f * v) : (v * v);
                __bf16 hb = (__bf16)x;
                h[j] = hb;
                l[j] = (__bf16)(x - (float)hb);
            }
            ahi[mt][ks] = h; alo[mt][ks] = l;
        }
    }

    // per-lane seed cutoffs for its 8 (mt,reg) query slots
    float sd[2][4];
    #pragma unroll
    for (int mt = 0; mt < 2; ++mt)
        #pragma unroll
        for (int r = 0; r < 4; ++r)
            sd[mt][r] = seeds[qbase + wv * 32 + mt * 16 + quad * 4 + r];

    int cnt_o = 0;                 // owner (tid<128): entries in my list
    if (tid < 2) cnt2[tid] = 0;

    const char* BsB = (const char*)Bs;
    int c = stripe;
    {
        const char* src = bprep + (size_t)c * CH_BYTES;
        #pragma unroll
        for (int i = 0; i < 8; ++i) {
            int s = tid + i * 256;
            async_cp16(src + s * 16, (void*)(BsB + s * 16));
        }
    }
    __syncthreads();   // Bs ready; cnt2 init visible

    for (int it = 0; it < CHUNKS_PER_BLK; ++it) {
        const int nbase = c * BC;
        const int cn    = c + PCH;
        const bool more = (it + 1) < CHUNKS_PER_BLK;
        const int p = it & 1;

        float2 ml[4];
        #pragma unroll
        for (int nt = 0; nt < 4; ++nt)
            ml[nt] = *(const float2*)&m2la[(size_t)(nbase + nt * 16 + mrow) * 2];

        f32x4 acc[2][4];
        #pragma unroll
        for (int nt = 0; nt < 4; ++nt) {
            f32x4 a0 = {0,0,0,0}, a1 = {0,0,0,0};
            #pragma unroll
            for (int ks = 0; ks < 4; ++ks) {
                bf16x8 bh = *(const bf16x8*)(BsB + nt * 4096 + ks * 1024 + lane * 16);
                bf16x8 bl = *(const bf16x8*)(BsB + SPLIT_OFF + nt * 4096 + ks * 1024 + lane * 16);
                a0 = __builtin_amdgcn_mfma_f32_16x16x32_bf16(ahi[0][ks], bh, a0, 0, 0, 0);
                a0 = __builtin_amdgcn_mfma_f32_16x16x32_bf16(ahi[0][ks], bl, a0, 0, 0, 0);
                a0 = __builtin_amdgcn_mfma_f32_16x16x32_bf16(alo[0][ks], bh, a0, 0, 0, 0);
                a1 = __builtin_amdgcn_mfma_f32_16x16x32_bf16(ahi[1][ks], bh, a1, 0, 0, 0);
                a1 = __builtin_amdgcn_mfma_f32_16x16x32_bf16(ahi[1][ks], bl, a1, 0, 0, 0);
                a1 = __builtin_amdgcn_mfma_f32_16x16x32_bf16(alo[1][ks], bh, a1, 0, 0, 0);
            }
            acc[0][nt] = a0; acc[1][nt] = a1;
        }
        __syncthreads();   // B1: frag reads done; Bs reusable

        if (more) {
            const char* src = bprep + (size_t)cn * CH_BYTES;
            #pragma unroll
            for (int i = 0; i < 8; ++i) {
                int s = tid + i * 256;
                async_cp16(src + s * 16, (void*)(BsB + s * 16));
            }
        }

        // ---- screen in C-layout registers vs static seed; append survivors ----
        #pragma unroll
        for (int mt = 0; mt < 2; ++mt)
            #pragma unroll
            for (int nt = 0; nt < 4; ++nt) {
                float m2 = ml[nt].x, la = ml[nt].y;
                #pragma unroll
                for (int r = 0; r < 4; ++r) {
                    float s = fmaf(nhit, acc[mt][nt][r] + m2, la);
                    if (s > sd[mt][r]) {
                        int pos = atomicAdd(&cnt2[p], 1);
                        if (pos < CAPB) {
                            int qs = wv * 32 + mt * 16 + quad * 4 + r;
                            int bi = nbase + nt * 16 + mrow;
                            buf[pos] = ((u64)map_f32(s) << 32) |
                                       ((u64)qs << 17) | (u64)bi;
                        }
                    }
                }
            }
        __syncthreads();   // B2: appends visible (also drains prefetch vmcnt)

        int cnt = cnt2[p];
        if (cnt > CAPB) cnt = CAPB;
        if (tid == 255) cnt2[p ^ 1] = 0;   // reset other slot for next chunk

        if (wv < 2) {   // owner phase: tid<128, one thread per query
            for (int e = 0; e < cnt; e += 4) {
                u64 k0 = buf[e];
                u64 k1 = (e + 1 < cnt) ? buf[e + 1] : 0ull;
                u64 k2 = (e + 2 < cnt) ? buf[e + 2] : 0ull;
                u64 k3 = (e + 3 < cnt) ? buf[e + 3] : 0ull;
                #pragma unroll
                for (int j = 0; j < 4; ++j) {
                    u64 k = (j == 0) ? k0 : (j == 1) ? k1 : (j == 2) ? k2 : k3;
                    if (e + j < cnt && ((int)(k >> 17) & 127) == tid) {
                        u64 kf = (k & 0xFFFFFFFF00000000ull) |
                                 (u64)(0xFFFFFFFFu - (unsigned)(k & 0x1FFFF));
                        if (cnt_o < KSEL) {
                            lists[tid * KSEL + cnt_o] = kf;
                            ++cnt_o;
                        } else {
                            u64 mn = lists[tid * KSEL]; int mp = 0;
                            #pragma unroll
                            for (int t = 1; t < KSEL; ++t) {
                                u64 v = lists[tid * KSEL + t];
                                if (v < mn) { mn = v; mp = t; }
                            }
                            if (kf > mn) lists[tid * KSEL + mp] = kf;
                        }
                    }
                }
            }
        }
        __syncthreads();   // B3: owner reads done; prefetched Bs ready
        c = cn;
    }

    // ---- write per-block candidates (owners' lists, zero-padded) ----
    if (tid < QT) {
        u64* dst = cand + (size_t)(qbase + tid) * CPQ + stripe * KSEL;
        #pragma unroll
        for (int i = 0; i < KSEL; ++i)
            dst[i] = (i < cnt_o) ? lists[tid * KSEL + i] : 0ull;
    }
}

// ---------------- global merge + exact recompute + compositing ----------------
__global__ __launch_bounds__(256)
void merge_composite_kernel(const float* __restrict__ query,
                            const float* __restrict__ mu,
                            const float* __restrict__ log_var,
                            const float* __restrict__ raw_alpha,
                            const float* __restrict__ features,
                            const float* __restrict__ log_tau_p,
                            const u64* __restrict__ cand,
                            float* __restrict__ out)
{
    const int q   = blockIdx.x;
    const int tid = threadIdx.x;
    const int wv = tid >> 6, lane = tid & 63;

    __shared__ u64   wtop[4 * KSEL];
    __shared__ int   sel[KSEL];
    __shared__ float w_sh[KSEL];
    __shared__ float mah[KSEL];
    __shared__ float alp[KSEL];

    u64 k[4];
    #pragma unroll
    for (int r = 0; r < 4; ++r)
        k[r] = cand[(size_t)q * CPQ + wv * 256 + r * 64 + lane];

    for (int r = 0; r < KSEL; ++r) {
        u64 m = k[0];
        #pragma unroll
        for (int j = 1; j < 4; ++j) if (k[j] > m) m = k[j];
        #pragma unroll
        for (int off = 32; off > 0; off >>= 1) {
            unsigned hi = __shfl_xor((unsigned)(m >> 32), off);
            unsigned lo = __shfl_xor((unsigned)(m & 0xFFFFFFFFu), off);
            u64 o = ((u64)hi << 32) | lo;
            if (o > m) m = o;
        }
        if (lane == 0) wtop[wv * KSEL + r] = m;
        #pragma unroll
        for (int j = 0; j < 4; ++j) if (k[j] == m) k[j] = 0ull;
    }
    __syncthreads();

    if (wv == 0) {
        u64 kk = wtop[lane];
        for (int r = 0; r < KSEL; ++r) {
            u64 m = kk;
            #pragma unroll
            for (int off = 32; off > 0; off >>= 1) {
                unsigned hi = __shfl_xor((unsigned)(m >> 32), off);
                unsigned lo = __shfl_xor((unsigned)(m & 0xFFFFFFFFu), off);
                u64 o = ((u64)hi << 32) | lo;
                if (o > m) m = o;
            }
            if (kk == m) kk = 0ull;
            if (lane == 0)
                sel[r] = (int)(0xFFFFFFFFu - (unsigned)(m & 0xFFFFFFFFull));
        }
    }
    __syncthreads();

    for (int r = wv; r < KSEL; r += 4) {
        int bi = sel[r];
        float qd = query[(size_t)q * DS + lane];
        float mv = mu[(size_t)bi * DS + lane];
        float d  = qd - mv;
        float t  = d * d * expf(-log_var[(size_t)bi * DS + lane]);
        #pragma unroll
        for (int off = 32; off > 0; off >>= 1) t += __shfl_down(t, off);
        if (lane == 0) {
            mah[r] = t;
            alp[r] = 1.0f / (1.0f + expf(-raw_alpha[bi]));
        }
    }
    __syncthreads();

    if (tid == 0) {
        float tau = expf(log_tau_p[0]);
        float cap = 0.3f / 16.0f;
        float logT = 0.0f;
        for (int r = 0; r < KSEL; ++r) {
            float K   = expf(-0.5f * mah[r] / tau);
            float eff = fminf(alp[r] * K, cap);
            w_sh[r]   = eff * expf(logT);
            logT     += log1pf(-fminf(eff, 1.0f - 1e-6f));
        }
        out[(size_t)BQ * DF + q] = expf(logT);
    }
    __syncthreads();

    {
        float a = 0.0f;
        #pragma unroll
        for (int r = 0; r < KSEL; ++r)
            a += w_sh[r] * features[(size_t)sel[r] * DF + tid];
        out[(size_t)q * DF + tid] = a;
    }
}

// ---------------- launch ----------------
extern "C" void kernel_launch(void* const* d_in, const int* in_sizes, int n_in,
                              void* d_out, int out_size, void* d_ws, size_t ws_size,
                              hipStream_t stream)
{
    (void)in_sizes; (void)n_in; (void)out_size; (void)ws_size;
    const float* query     = (const float*)d_in[0];
    const float* mu        = (const float*)d_in[1];
    const float* log_var   = (const float*)d_in[2];
    const float* raw_alpha = (const float*)d_in[3];
    const float* features  = (const float*)d_in[4];
    const float* log_tau   = (const float*)d_in[5];
    float* out = (float*)d_out;

    // ws layout: Bprep 64 MB | m2la 1 MB | cand 8 MB | seeds 4 KB
    char*  bprep = (char*)d_ws;
    float* m2la  = (float*)((char*)d_ws + (size_t)NCHUNK * CH_BYTES);
    u64*   cand  = (u64*)((char*)d_ws + (size_t)NCHUNK * CH_BYTES + (size_t)NB * 2 * 4);
    float* seeds = (float*)((char*)cand + (size_t)BQ * CPQ * 8);

    prep_kernel<<<NCHUNK * 4, 256, 0, stream>>>(mu, log_var, raw_alpha, bprep, m2la);
    sample_kernel<<<BQ / QT, 256, 0, stream>>>(query, bprep, m2la, log_tau, seeds);
    score_topk_kernel<<<PCH * (BQ / QT), 256, 0, stream>>>(query, bprep, m2la,
                                                           log_tau, seeds, cand);
    merge_composite_kernel<<<BQ, 256, 0, stream>>>(query, mu, log_var, raw_alpha,
                                                   features, log_tau, cand, out);
}